// Round 17
// baseline (45.531 us; speedup 1.0000x reference)
//
#include <hip/hip_runtime.h>

#define B 2
#define N 16384
#define NPOINT 4096
#define C 64
#define NSAMPLE 32

#define NCELL 1000        // 10x10x10 grid, cell size 0.1 == radius
#define CELLW_STRIDE 1024 // work array stride per batch
#define OFF_STRIDE 1056   // offsets stride per batch (1001 used)
#define CAP 192           // per-query candidate capacity (mean ~69)

#define HIST_BLOCKS ((B * (N + NPOINT) + 255) / 256)  // 160
#define TRANS_BLOCKS (B * (N / 64))                   // 512

#define PTS_BLK_PER_B (N / 256)       // 64
#define Q_BLK_PER_B (NPOINT / 256)    // 16
#define SS_BLOCKS (B * (PTS_BLK_PER_B + Q_BLK_PER_B))  // 160

typedef __attribute__((ext_vector_type(4))) float f32x4;

// Threshold exactly as the JAX/numpy reference sees it:
// float32(double(0.1)*double(0.1)) = 0.009999999776482582f
__device__ __forceinline__ float r2_thresh() { return (float)(0.1 * 0.1); }

__device__ __forceinline__ int clamp09(int v) { return v < 0 ? 0 : (v > 9 ? 9 : v); }

__device__ __forceinline__ int cell_of(float x, float y, float z) {
    const int ix = clamp09((int)floorf(x * 10.0f));
    const int iy = clamp09((int)floorf(y * 10.0f));
    const int iz = clamp09((int)floorf(z * 10.0f));
    return (ix * 10 + iy) * 10 + iz;
}

// ---------------- Kernel H: histogram (blocks 0..159) ∥ transpose (160..671) ----------------
__global__ void __launch_bounds__(256) hist_transpose_kernel(
    const float* __restrict__ xyz, const float* __restrict__ new_xyz,
    int* __restrict__ cellwork, int* __restrict__ qwork,
    const float* __restrict__ feat, float* __restrict__ ft) {
    __shared__ float tile[64 * 65];
    const int t = threadIdx.x;

    if (blockIdx.x >= HIST_BLOCKS) {
        // ---- transpose branch ----
        const int tb = blockIdx.x - HIST_BLOCKS;    // 0..511
        const int b = tb / (N / 64);
        const int n0 = (tb % (N / 64)) * 64;
        const int l = t & 63;
        const int w = t >> 6;
#pragma unroll
        for (int it = 0; it < 16; ++it) {
            const int c = it * 4 + w;
            tile[c * 65 + l] = feat[((size_t)b * C + c) * N + n0 + l];
        }
        __syncthreads();
#pragma unroll
        for (int it = 0; it < 16; ++it) {
            const int nn = it * 4 + w;
            ft[((size_t)b * N + n0 + nn) * C + l] = tile[l * 65 + nn];
        }
        return;
    }

    const int i = blockIdx.x * blockDim.x + t;  // over B*(N+NPOINT)
    if (i < B * N) {
        const int b = i / N;
        const float x = xyz[(size_t)i * 3 + 0];
        const float y = xyz[(size_t)i * 3 + 1];
        const float z = xyz[(size_t)i * 3 + 2];
        atomicAdd(&cellwork[b * CELLW_STRIDE + cell_of(x, y, z)], 1);
    } else if (i < B * (N + NPOINT)) {
        const int qi = i - B * N;
        const int b = qi / NPOINT;
        const float x = new_xyz[(size_t)qi * 3 + 0];
        const float y = new_xyz[(size_t)qi * 3 + 1];
        const float z = new_xyz[(size_t)qi * 3 + 2];
        atomicAdd(&qwork[b * CELLW_STRIDE + cell_of(x, y, z)], 1);
    }
}

// ---------------- Kernel SC: scatter with per-block redundant LDS scan ----------------
__global__ void __launch_bounds__(256) scan_scatter_kernel(
    const float* __restrict__ xyz, const float* __restrict__ new_xyz,
    const int* __restrict__ cellwork, const int* __restrict__ qwork,
    int* __restrict__ off, float4* __restrict__ binned, int* __restrict__ qperm,
    int* __restrict__ gcur, int* __restrict__ qgcur) {
    __shared__ int lds_off[1024];
    __shared__ int wsum[4];

    const int t = threadIdx.x;
    const int lane = t & 63;
    const int w = t >> 6;   // 4 waves
    const int blk = blockIdx.x;

    const bool is_pts = (blk < B * PTS_BLK_PER_B);
    int b, k;
    const int* cnt;
    int* gc;
    if (is_pts) {
        b = blk / PTS_BLK_PER_B;
        k = blk % PTS_BLK_PER_B;
        cnt = cellwork + b * CELLW_STRIDE;
        gc = gcur + b * CELLW_STRIDE;
    } else {
        const int q = blk - B * PTS_BLK_PER_B;
        b = q / Q_BLK_PER_B;
        k = q % Q_BLK_PER_B;
        cnt = qwork + b * CELLW_STRIDE;
        gc = qgcur + b * CELLW_STRIDE;
    }

    // thread-local prefix over 4 cells (cells 1000..1023 are zero)
    const int4 c4 = *(const int4*)(cnt + 4 * t);
    const int i0 = c4.x;
    const int i1 = i0 + c4.y;
    const int i2 = i1 + c4.z;
    const int i3 = i2 + c4.w;

    // inclusive wave scan of thread sums
    int ws = i3;
#pragma unroll
    for (int d = 1; d < 64; d <<= 1) {
        const int u = __shfl_up(ws, d, 64);
        if (lane >= d) ws += u;
    }
    if (lane == 63) wsum[w] = ws;
    __syncthreads();
    int wpre = 0;
#pragma unroll
    for (int x = 0; x < 4; ++x) {
        const int v = wsum[x];
        if (x < w) wpre += v;
    }
    const int base = wpre + (ws - i3);  // exclusive prefix of this thread's first cell
    lds_off[4 * t + 0] = base;
    lds_off[4 * t + 1] = base + i0;
    lds_off[4 * t + 2] = base + i1;
    lds_off[4 * t + 3] = base + i2;
    __syncthreads();

    if (is_pts && k == 0) {  // publish offsets for fused kernel (incl. off[1000]=N)
#pragma unroll
        for (int jj = 0; jj < 4; ++jj) {
            const int idx = 4 * t + jj;
            if (idx <= NCELL) off[b * OFF_STRIDE + idx] = lds_off[idx];
        }
    }

    // scatter: one element per thread
    const int i = k * 256 + t;
    if (is_pts) {
        const float x = xyz[((size_t)b * N + i) * 3 + 0];
        const float y = xyz[((size_t)b * N + i) * 3 + 1];
        const float z = xyz[((size_t)b * N + i) * 3 + 2];
        const int c = cell_of(x, y, z);
        const int pos = lds_off[c] + atomicAdd(&gc[c], 1);
        float4 pv;
        pv.x = x; pv.y = y; pv.z = z; pv.w = __int_as_float(i);
        binned[(size_t)b * N + pos] = pv;
    } else {
        const float x = new_xyz[((size_t)b * NPOINT + i) * 3 + 0];
        const float y = new_xyz[((size_t)b * NPOINT + i) * 3 + 1];
        const float z = new_xyz[((size_t)b * NPOINT + i) * 3 + 2];
        const int c = cell_of(x, y, z);
        const int pos = lds_off[c] + atomicAdd(&gc[c], 1);
        qperm[b * NPOINT + pos] = i;
    }
}

// ---------------- exact linear-scan fallback (in-wave); out may be LDS or global ----------------
__device__ void linear_ball_fallback(const float* __restrict__ xb,
                                     float cx, float cy, float cz,
                                     int lane, unsigned long long lanemask_lt,
                                     int* out) {
    const float r2 = r2_thresh();
    int cnt = 0, first_idx = 0;
    for (int base = 0; base < N; base += 64) {
        const int i = base + lane;
        const float x = xb[i * 3 + 0];
        const float y = xb[i * 3 + 1];
        const float z = xb[i * 3 + 2];
        float d2;
        {
#pragma clang fp contract(off)
            float dx = x - cx;
            float dy = y - cy;
            float dz = z - cz;
            d2 = dx * dx + dy * dy + dz * dz;
        }
        const bool in = d2 < r2;
        const unsigned long long m = __ballot(in);
        if (in) {
            const int pos = cnt + __popcll(m & lanemask_lt);
            if (pos < NSAMPLE) out[pos] = i;
        }
        if (cnt == 0 && m != 0ull) first_idx = base + __builtin_ctzll(m);
        cnt += __popcll(m);
        if (cnt >= NSAMPLE) break;
    }
    if (cnt < NSAMPLE) {
        if (cnt == 0) first_idx = 0;
        for (int pos = cnt + lane; pos < NSAMPLE; pos += 64) out[pos] = first_idx;
    }
}

// Rank-select the NSAMPLE smallest indices from cand[0..K) (K <= CAP) -> out.
// cand has 4 sentinel slots past K (row size CAP+4); int4 LDS broadcast loads.
__device__ __forceinline__ void rank_select(int* cand, int K, int lane,
                                            int* out) {
    if (lane < 4) cand[K + lane] = 0x7FFFFFFF;   // sentinels for int4 overrun
    const int e0 = (lane < K) ? cand[lane] : 0x7FFFFFFF;
    const int e1 = (64 + lane < K) ? cand[64 + lane] : 0x7FFFFFFF;
    const int e2 = (128 + lane < K) ? cand[128 + lane] : 0x7FFFFFFF;
    int r0 = 0, r1 = 0, r2i = 0;
    if (K <= 64) {
        for (int k = 0; k < K; k += 4) {
            const int4 v = *(const int4*)(cand + k);
            r0 += (v.x < e0) + (v.y < e0) + (v.z < e0) + (v.w < e0);
        }
    } else if (K <= 128) {
        for (int k = 0; k < K; k += 4) {
            const int4 v = *(const int4*)(cand + k);
            r0 += (v.x < e0) + (v.y < e0) + (v.z < e0) + (v.w < e0);
            r1 += (v.x < e1) + (v.y < e1) + (v.z < e1) + (v.w < e1);
        }
    } else {
        for (int k = 0; k < K; k += 4) {
            const int4 v = *(const int4*)(cand + k);
            r0 += (v.x < e0) + (v.y < e0) + (v.z < e0) + (v.w < e0);
            r1 += (v.x < e1) + (v.y < e1) + (v.z < e1) + (v.w < e1);
            r2i += (v.x < e2) + (v.y < e2) + (v.z < e2) + (v.w < e2);
        }
    }
    if (lane < K && r0 < NSAMPLE) out[r0] = e0;
    if (64 + lane < K && r1 < NSAMPLE) out[r1] = e1;
    if (128 + lane < K && r2i < NSAMPLE) out[r2i] = e2;

    if (K < NSAMPLE) {
        int mn = min(e0, min(e1, e2));
#pragma unroll
        for (int d = 32; d; d >>= 1) mn = min(mn, __shfl_xor(mn, d));
        const int fill = (K > 0) ? mn : 0;
        for (int pos = K + lane; pos < NSAMPLE; pos += 64) out[pos] = fill;
    }
}

// Scan one window against one center; append in-ball ids to cand; returns K.
__device__ __forceinline__ int scan_window(
    const float4* __restrict__ bb, const int* __restrict__ ob,
    int lox, int hix, int loy, int hiy, int loz, int hiz,
    float cx, float cy, float cz, int lane,
    unsigned long long lanemask_lt, int* cand)
{
    const float r2 = r2_thresh();
    int K = 0;
    for (int ix = lox; ix <= hix; ++ix) {
        for (int iy = loy; iy <= hiy; ++iy) {
            const int rowc = (ix * 10 + iy) * 10;
            const int s0 = ob[rowc + loz];
            const int s1 = ob[rowc + hiz + 1];  // z cells contiguous -> one segment
            for (int cur = s0; cur < s1; cur += 64) {
                const int i = cur + lane;
                const bool valid = (i < s1);
                float4 pv;
                if (valid) pv = bb[i];
                else { pv.x = 1e9f; pv.y = 1e9f; pv.z = 1e9f; pv.w = 0.0f; }
                float d2;
                {
#pragma clang fp contract(off)
                    float dx = pv.x - cx, dy = pv.y - cy, dz = pv.z - cz;
                    d2 = dx * dx + dy * dy + dz * dz;
                }
                const bool in = valid && (d2 < r2);
                const unsigned long long m = __ballot(in);
                if (in) {
                    const int pos = K + __popcll(m & lanemask_lt);
                    if (pos < CAP) cand[pos] = __float_as_int(pv.w);
                }
                K += __popcll(m);
            }
        }
    }
    return K;
}

// ---------------- Kernel F: fused ball query + grouping ----------------
// 256 threads = 4 waves = 4 consecutive sorted queries. Ball query into LDS;
// group phase in TWO passes of 64 pairs reusing one sf buffer. LDS 20,304 B
// -> 8 blocks/CU = 32 waves/CU (wave cap). Output stores are NON-TEMPORAL:
// out is write-once/never-read, and 70 MB of write-allocate traffic through
// the 4 MB/XCD L2 would evict the ft gather working set.
__global__ void __launch_bounds__(256) fused_kernel(
    const float4* __restrict__ binned,   // (B, N)
    const int* __restrict__ off,         // (B, OFF_STRIDE)
    const float* __restrict__ new_xyz,   // (B, NPOINT, 3)
    const float* __restrict__ xyz,       // (B, N, 3)
    const float* __restrict__ ft,        // (B, N, C)
    const int* __restrict__ qperm,       // (B, NPOINT)
    float* __restrict__ out)             // (B, 3+C, NPOINT, NSAMPLE)
{
    __shared__ int cand_s[4][CAP + 4];  // 3136 B (4 sentinel slots per wave)
    __shared__ int sidx[4 * NSAMPLE];   // 512 B
    __shared__ int sj[4];               // 16 B
    __shared__ float sf[64 * 65];       // 16640 B   (total 20304 B)

    const int t = threadIdx.x;
    const int lane = t & 63;
    const int w = t >> 6;   // wave = local query

    const int nwg = B * NPOINT / 4;                 // 2048, % 8 == 0
    const int g = blockIdx.x;
    const int swz = (g & 7) * (nwg / 8) + (g >> 3); // bijective XCD swizzle
    const int b = swz / (NPOINT / 4);
    const int p4 = swz % (NPOINT / 4);

    const int j = qperm[b * NPOINT + p4 * 4 + w];   // original query (broadcast)
    if (lane == 0) sj[w] = j;

    const float cx = new_xyz[((size_t)b * NPOINT + j) * 3 + 0];
    const float cy = new_xyz[((size_t)b * NPOINT + j) * 3 + 1];
    const float cz = new_xyz[((size_t)b * NPOINT + j) * 3 + 2];

    int* cand = cand_s[w];
    int* sout = sidx + w * NSAMPLE;
    const float4* __restrict__ bb = binned + (size_t)b * N;
    const int* __restrict__ ob = off + b * OFF_STRIDE;

    const unsigned long long lanemask_lt = (lane == 63) ? 0x7FFFFFFFFFFFFFFFull
                                                        : ((1ull << lane) - 1ull);

    const int lox = max(0, (int)floorf((cx - 0.1001f) * 10.0f));
    const int hix = min(9, (int)floorf((cx + 0.1001f) * 10.0f));
    const int loy = max(0, (int)floorf((cy - 0.1001f) * 10.0f));
    const int hiy = min(9, (int)floorf((cy + 0.1001f) * 10.0f));
    const int loz = max(0, (int)floorf((cz - 0.1001f) * 10.0f));
    const int hiz = min(9, (int)floorf((cz + 0.1001f) * 10.0f));

    const int K = scan_window(bb, ob, lox, hix, loy, hiy, loz, hiz,
                              cx, cy, cz, lane, lanemask_lt, cand);

    if (K > CAP) {  // pathological density: exact linear rescan (wave-uniform)
        linear_ball_fallback(xyz + (size_t)b * N * 3, cx, cy, cz, lane, lanemask_lt, sout);
    } else {
        rank_select(cand, K, lane, sout);
    }
    __syncthreads();

    const size_t plane = (size_t)NPOINT * NSAMPLE;
    const size_t bbase = (size_t)b * (3 + C) * plane;

    // xyz part: threads 0..127 -> one (query,slot) pair each (nt stores)
    if (t < 128) {
        const int id = sidx[t];
        const int jq = sj[t >> 5];
        const int s = t & 31;
        const size_t cb = ((size_t)b * NPOINT + jq) * 3;
        const size_t pb = ((size_t)b * N + id) * 3;
        const size_t obx = bbase + (size_t)jq * NSAMPLE + s;
        {
#pragma clang fp contract(off)
            const float px = xyz[pb + 0] - new_xyz[cb + 0];
            const float py = xyz[pb + 1] - new_xyz[cb + 1];
            const float pz = xyz[pb + 2] - new_xyz[cb + 2];
            __builtin_nontemporal_store(px, out + obx + 0 * plane);
            __builtin_nontemporal_store(py, out + obx + 1 * plane);
            __builtin_nontemporal_store(pz, out + obx + 2 * plane);
        }
    }

    // group phase: two passes of 64 pairs (queries 2h, 2h+1), sf reused
#pragma unroll
    for (int h = 0; h < 2; ++h) {
        const int* sidxL = sidx + h * 64;
        // gather: 64 pairs x 16 lanes, one float4 each, 4 iterations
        {
            const int lane16 = t & 15;
            const int pg = t >> 4;  // 0..15
#pragma unroll
            for (int it = 0; it < 4; ++it) {
                const int pp = it * 16 + pg;
                const int id = sidxL[pp];
                const float4 v = *(const float4*)(ft + ((size_t)b * N + id) * C + lane16 * 4);
                float* dst = sf + pp * 65 + lane16 * 4;
                dst[0] = v.x; dst[1] = v.y; dst[2] = v.z; dst[3] = v.w;
            }
        }
        __syncthreads();
        // store: float4 per thread = 4 samples of one channel (non-temporal).
        {
            const int f = t & 15;
            const int rl = f >> 3;           // local row 0/1 within this h-pass
            const int s0 = (f & 7) * 4;      // starting sample of the quad
            const int q = sj[2 * h + rl];
            const size_t rowb = bbase + (size_t)q * NSAMPLE + s0;
            const int prow = (rl * 32 + s0) * 65;   // sf row base for this quad
#pragma unroll
            for (int it = 0; it < 4; ++it) {
                const int c = it * 16 + (t >> 4);
                f32x4 v;
                v.x = sf[prow + 0 * 65 + c];
                v.y = sf[prow + 1 * 65 + c];
                v.z = sf[prow + 2 * 65 + c];
                v.w = sf[prow + 3 * 65 + c];
                __builtin_nontemporal_store(v, (f32x4*)(out + rowb + (size_t)(3 + c) * plane));
            }
        }
        __syncthreads();  // before sf reuse in next pass
    }
}

// ---------------- ws-too-small fallbacks (linear ball + direct group) ----------------
__global__ void __launch_bounds__(256) ball_query_kernel(
    const float* __restrict__ xyz, const float* __restrict__ new_xyz,
    int* __restrict__ idx_out)
{
    const int wave = (blockIdx.x * blockDim.x + threadIdx.x) >> 6;
    const int lane = threadIdx.x & 63;
    if (wave >= B * NPOINT) return;
    const int b = wave / NPOINT;
    const float cx = new_xyz[(size_t)wave * 3 + 0];
    const float cy = new_xyz[(size_t)wave * 3 + 1];
    const float cz = new_xyz[(size_t)wave * 3 + 2];
    const unsigned long long lanemask_lt = (lane == 63) ? 0x7FFFFFFFFFFFFFFFull
                                                        : ((1ull << lane) - 1ull);
    linear_ball_fallback(xyz + (size_t)b * N * 3, cx, cy, cz, lane, lanemask_lt,
                         idx_out + (size_t)wave * NSAMPLE);
}

__global__ void __launch_bounds__(256) group_kernel(
    const float* __restrict__ xyz, const float* __restrict__ new_xyz,
    const float* __restrict__ feat, const int* __restrict__ idx_arr,
    float* __restrict__ out) {
    const int t = threadIdx.x;
    const int s = t & 31;
    const int jl = t >> 5;
    const int j = blockIdx.x * 8 + jl;
    const int b = blockIdx.y;

    const int id = idx_arr[((size_t)b * NPOINT + j) * NSAMPLE + s];

    const float px = xyz[((size_t)b * N + id) * 3 + 0] - new_xyz[((size_t)b * NPOINT + j) * 3 + 0];
    const float py = xyz[((size_t)b * N + id) * 3 + 1] - new_xyz[((size_t)b * NPOINT + j) * 3 + 1];
    const float pz = xyz[((size_t)b * N + id) * 3 + 2] - new_xyz[((size_t)b * NPOINT + j) * 3 + 2];

    const size_t plane = (size_t)NPOINT * NSAMPLE;
    const size_t obase = (size_t)b * (3 + C) * plane + (size_t)j * NSAMPLE + s;

    out[obase + 0 * plane] = px;
    out[obase + 1 * plane] = py;
    out[obase + 2 * plane] = pz;

    const float* __restrict__ fb = feat + (size_t)b * C * N;
#pragma unroll 8
    for (int c = 0; c < C; ++c) {
        out[obase + (size_t)(3 + c) * plane] = fb[(size_t)c * N + id];
    }
}

extern "C" void kernel_launch(void* const* d_in, const int* in_sizes, int n_in,
                              void* d_out, int out_size, void* d_ws, size_t ws_size,
                              hipStream_t stream) {
    const float* xyz     = (const float*)d_in[0];  // (B, N, 3)
    const float* new_xyz = (const float*)d_in[1];  // (B, NPOINT, 3)
    const float* feat    = (const float*)d_in[2];  // (B, C, N)
    float* out = (float*)d_out;

    // Workspace layout (contiguous; all segments 16B-aligned)
    const size_t idx_bytes    = (size_t)B * NPOINT * NSAMPLE * sizeof(int);  // fallback only
    const size_t ft_bytes     = (size_t)B * N * C * sizeof(float);           // 8,388,608
    const size_t binned_bytes = (size_t)B * N * sizeof(float4);              //   524,288
    const size_t off_bytes    = (size_t)B * OFF_STRIDE * sizeof(int);        //     8,448
    const size_t cellw_bytes  = (size_t)B * CELLW_STRIDE * sizeof(int);      //     8,192
    const size_t qwork_bytes  = (size_t)B * CELLW_STRIDE * sizeof(int);      //     8,192
    const size_t gcur_bytes   = (size_t)B * CELLW_STRIDE * sizeof(int);      //     8,192
    const size_t qgcur_bytes  = (size_t)B * CELLW_STRIDE * sizeof(int);      //     8,192
    const size_t qperm_bytes  = (size_t)B * NPOINT * sizeof(int);            //    32,768

    char* ws = (char*)d_ws;
    size_t o = 0;
    int*    idx_ws   = (int*)(ws + o);    o += idx_bytes;
    float*  ft       = (float*)(ws + o);  o += ft_bytes;
    float4* binned   = (float4*)(ws + o); o += binned_bytes;
    int*    off      = (int*)(ws + o);    o += off_bytes;
    int*    cellwork = (int*)(ws + o);    o += cellw_bytes;   // cellwork,qwork,gcur,qgcur adjacent
    int*    qwork    = (int*)(ws + o);    o += qwork_bytes;
    int*    gcur     = (int*)(ws + o);    o += gcur_bytes;
    int*    qgcur    = (int*)(ws + o);    o += qgcur_bytes;
    int*    qperm    = (int*)(ws + o);    o += qperm_bytes;

    const bool use_grid = (ws_size >= o);

    if (use_grid) {
        // zero histograms + global cursors (adjacent, one memset)
        hipMemsetAsync(cellwork, 0, cellw_bytes + qwork_bytes + gcur_bytes + qgcur_bytes, stream);
        hist_transpose_kernel<<<HIST_BLOCKS + TRANS_BLOCKS, 256, 0, stream>>>(
            xyz, new_xyz, cellwork, qwork, feat, ft);
        scan_scatter_kernel<<<SS_BLOCKS, 256, 0, stream>>>(
            xyz, new_xyz, cellwork, qwork, off, binned, qperm, gcur, qgcur);
        fused_kernel<<<B * NPOINT / 4, 256, 0, stream>>>(
            binned, off, new_xyz, xyz, ft, qperm, out);
    } else {
        ball_query_kernel<<<(B * NPOINT) / 4, 256, 0, stream>>>(xyz, new_xyz, idx_ws);
        dim3 grid2(NPOINT / 8, B);
        group_kernel<<<grid2, 256, 0, stream>>>(xyz, new_xyz, feat, idx_ws, out);
    }
}

// Round 18
// 43.750 us; speedup vs baseline: 1.0407x; 1.0407x over previous
//
#include <hip/hip_runtime.h>

#define B 2
#define N 16384
#define NPOINT 4096
#define C 64
#define NSAMPLE 32

#define NCELL 1000        // 10x10x10 grid, cell size 0.1 == radius
#define CELLW_STRIDE 1024 // work array stride per batch
#define OFF_STRIDE 1056   // offsets stride per batch (1001 used)
#define CAP 192           // per-query candidate capacity (mean ~69)

#define HIST_BLOCKS ((B * (N + NPOINT) + 255) / 256)  // 160
#define TRANS_BLOCKS (B * (N / 64))                   // 512

#define PTS_BLK_PER_B (N / 256)       // 64
#define Q_BLK_PER_B (NPOINT / 256)    // 16
#define SS_BLOCKS (B * (PTS_BLK_PER_B + Q_BLK_PER_B))  // 160

// Threshold exactly as the JAX/numpy reference sees it:
// float32(double(0.1)*double(0.1)) = 0.009999999776482582f
__device__ __forceinline__ float r2_thresh() { return (float)(0.1 * 0.1); }

__device__ __forceinline__ int clamp09(int v) { return v < 0 ? 0 : (v > 9 ? 9 : v); }

__device__ __forceinline__ int cell_of(float x, float y, float z) {
    const int ix = clamp09((int)floorf(x * 10.0f));
    const int iy = clamp09((int)floorf(y * 10.0f));
    const int iz = clamp09((int)floorf(z * 10.0f));
    return (ix * 10 + iy) * 10 + iz;
}

// ---------------- Kernel H: histogram (blocks 0..159) ∥ transpose (160..671) ----------------
__global__ void __launch_bounds__(256) hist_transpose_kernel(
    const float* __restrict__ xyz, const float* __restrict__ new_xyz,
    int* __restrict__ cellwork, int* __restrict__ qwork,
    const float* __restrict__ feat, float* __restrict__ ft) {
    __shared__ float tile[64 * 65];
    const int t = threadIdx.x;

    if (blockIdx.x >= HIST_BLOCKS) {
        // ---- transpose branch ----
        const int tb = blockIdx.x - HIST_BLOCKS;    // 0..511
        const int b = tb / (N / 64);
        const int n0 = (tb % (N / 64)) * 64;
        const int l = t & 63;
        const int w = t >> 6;
#pragma unroll
        for (int it = 0; it < 16; ++it) {
            const int c = it * 4 + w;
            tile[c * 65 + l] = feat[((size_t)b * C + c) * N + n0 + l];
        }
        __syncthreads();
#pragma unroll
        for (int it = 0; it < 16; ++it) {
            const int nn = it * 4 + w;
            ft[((size_t)b * N + n0 + nn) * C + l] = tile[l * 65 + nn];
        }
        return;
    }

    const int i = blockIdx.x * blockDim.x + t;  // over B*(N+NPOINT)
    if (i < B * N) {
        const int b = i / N;
        const float x = xyz[(size_t)i * 3 + 0];
        const float y = xyz[(size_t)i * 3 + 1];
        const float z = xyz[(size_t)i * 3 + 2];
        atomicAdd(&cellwork[b * CELLW_STRIDE + cell_of(x, y, z)], 1);
    } else if (i < B * (N + NPOINT)) {
        const int qi = i - B * N;
        const int b = qi / NPOINT;
        const float x = new_xyz[(size_t)qi * 3 + 0];
        const float y = new_xyz[(size_t)qi * 3 + 1];
        const float z = new_xyz[(size_t)qi * 3 + 2];
        atomicAdd(&qwork[b * CELLW_STRIDE + cell_of(x, y, z)], 1);
    }
}

// ---------------- Kernel SC: scatter with per-block redundant LDS scan ----------------
__global__ void __launch_bounds__(256) scan_scatter_kernel(
    const float* __restrict__ xyz, const float* __restrict__ new_xyz,
    const int* __restrict__ cellwork, const int* __restrict__ qwork,
    int* __restrict__ off, float4* __restrict__ binned, int* __restrict__ qperm,
    int* __restrict__ gcur, int* __restrict__ qgcur) {
    __shared__ int lds_off[1024];
    __shared__ int wsum[4];

    const int t = threadIdx.x;
    const int lane = t & 63;
    const int w = t >> 6;   // 4 waves
    const int blk = blockIdx.x;

    const bool is_pts = (blk < B * PTS_BLK_PER_B);
    int b, k;
    const int* cnt;
    int* gc;
    if (is_pts) {
        b = blk / PTS_BLK_PER_B;
        k = blk % PTS_BLK_PER_B;
        cnt = cellwork + b * CELLW_STRIDE;
        gc = gcur + b * CELLW_STRIDE;
    } else {
        const int q = blk - B * PTS_BLK_PER_B;
        b = q / Q_BLK_PER_B;
        k = q % Q_BLK_PER_B;
        cnt = qwork + b * CELLW_STRIDE;
        gc = qgcur + b * CELLW_STRIDE;
    }

    // thread-local prefix over 4 cells (cells 1000..1023 are zero)
    const int4 c4 = *(const int4*)(cnt + 4 * t);
    const int i0 = c4.x;
    const int i1 = i0 + c4.y;
    const int i2 = i1 + c4.z;
    const int i3 = i2 + c4.w;

    // inclusive wave scan of thread sums
    int ws = i3;
#pragma unroll
    for (int d = 1; d < 64; d <<= 1) {
        const int u = __shfl_up(ws, d, 64);
        if (lane >= d) ws += u;
    }
    if (lane == 63) wsum[w] = ws;
    __syncthreads();
    int wpre = 0;
#pragma unroll
    for (int x = 0; x < 4; ++x) {
        const int v = wsum[x];
        if (x < w) wpre += v;
    }
    const int base = wpre + (ws - i3);  // exclusive prefix of this thread's first cell
    lds_off[4 * t + 0] = base;
    lds_off[4 * t + 1] = base + i0;
    lds_off[4 * t + 2] = base + i1;
    lds_off[4 * t + 3] = base + i2;
    __syncthreads();

    if (is_pts && k == 0) {  // publish offsets for fused kernel (incl. off[1000]=N)
#pragma unroll
        for (int jj = 0; jj < 4; ++jj) {
            const int idx = 4 * t + jj;
            if (idx <= NCELL) off[b * OFF_STRIDE + idx] = lds_off[idx];
        }
    }

    // scatter: one element per thread
    const int i = k * 256 + t;
    if (is_pts) {
        const float x = xyz[((size_t)b * N + i) * 3 + 0];
        const float y = xyz[((size_t)b * N + i) * 3 + 1];
        const float z = xyz[((size_t)b * N + i) * 3 + 2];
        const int c = cell_of(x, y, z);
        const int pos = lds_off[c] + atomicAdd(&gc[c], 1);
        float4 pv;
        pv.x = x; pv.y = y; pv.z = z; pv.w = __int_as_float(i);
        binned[(size_t)b * N + pos] = pv;
    } else {
        const float x = new_xyz[((size_t)b * NPOINT + i) * 3 + 0];
        const float y = new_xyz[((size_t)b * NPOINT + i) * 3 + 1];
        const float z = new_xyz[((size_t)b * NPOINT + i) * 3 + 2];
        const int c = cell_of(x, y, z);
        const int pos = lds_off[c] + atomicAdd(&gc[c], 1);
        qperm[b * NPOINT + pos] = i;
    }
}

// ---------------- exact linear-scan fallback (in-wave); out may be LDS or global ----------------
__device__ void linear_ball_fallback(const float* __restrict__ xb,
                                     float cx, float cy, float cz,
                                     int lane, unsigned long long lanemask_lt,
                                     int* out) {
    const float r2 = r2_thresh();
    int cnt = 0, first_idx = 0;
    for (int base = 0; base < N; base += 64) {
        const int i = base + lane;
        const float x = xb[i * 3 + 0];
        const float y = xb[i * 3 + 1];
        const float z = xb[i * 3 + 2];
        float d2;
        {
#pragma clang fp contract(off)
            float dx = x - cx;
            float dy = y - cy;
            float dz = z - cz;
            d2 = dx * dx + dy * dy + dz * dz;
        }
        const bool in = d2 < r2;
        const unsigned long long m = __ballot(in);
        if (in) {
            const int pos = cnt + __popcll(m & lanemask_lt);
            if (pos < NSAMPLE) out[pos] = i;
        }
        if (cnt == 0 && m != 0ull) first_idx = base + __builtin_ctzll(m);
        cnt += __popcll(m);
        if (cnt >= NSAMPLE) break;
    }
    if (cnt < NSAMPLE) {
        if (cnt == 0) first_idx = 0;
        for (int pos = cnt + lane; pos < NSAMPLE; pos += 64) out[pos] = first_idx;
    }
}

// Rank-select the NSAMPLE smallest indices from cand[0..K) (K <= CAP) -> out.
// cand has 4 sentinel slots past K (row size CAP+4); int4 LDS broadcast loads.
__device__ __forceinline__ void rank_select(int* cand, int K, int lane,
                                            int* out) {
    if (lane < 4) cand[K + lane] = 0x7FFFFFFF;   // sentinels for int4 overrun
    const int e0 = (lane < K) ? cand[lane] : 0x7FFFFFFF;
    const int e1 = (64 + lane < K) ? cand[64 + lane] : 0x7FFFFFFF;
    const int e2 = (128 + lane < K) ? cand[128 + lane] : 0x7FFFFFFF;
    int r0 = 0, r1 = 0, r2i = 0;
    if (K <= 64) {
        for (int k = 0; k < K; k += 4) {
            const int4 v = *(const int4*)(cand + k);
            r0 += (v.x < e0) + (v.y < e0) + (v.z < e0) + (v.w < e0);
        }
    } else if (K <= 128) {
        for (int k = 0; k < K; k += 4) {
            const int4 v = *(const int4*)(cand + k);
            r0 += (v.x < e0) + (v.y < e0) + (v.z < e0) + (v.w < e0);
            r1 += (v.x < e1) + (v.y < e1) + (v.z < e1) + (v.w < e1);
        }
    } else {
        for (int k = 0; k < K; k += 4) {
            const int4 v = *(const int4*)(cand + k);
            r0 += (v.x < e0) + (v.y < e0) + (v.z < e0) + (v.w < e0);
            r1 += (v.x < e1) + (v.y < e1) + (v.z < e1) + (v.w < e1);
            r2i += (v.x < e2) + (v.y < e2) + (v.z < e2) + (v.w < e2);
        }
    }
    if (lane < K && r0 < NSAMPLE) out[r0] = e0;
    if (64 + lane < K && r1 < NSAMPLE) out[r1] = e1;
    if (128 + lane < K && r2i < NSAMPLE) out[r2i] = e2;

    if (K < NSAMPLE) {
        int mn = min(e0, min(e1, e2));
#pragma unroll
        for (int d = 32; d; d >>= 1) mn = min(mn, __shfl_xor(mn, d));
        const int fill = (K > 0) ? mn : 0;
        for (int pos = K + lane; pos < NSAMPLE; pos += 64) out[pos] = fill;
    }
}

// Scan the window against one center. Segment bounds for ALL <=9 (x,y)
// segments are fetched lane-parallel up front (one memory latency instead of
// one per segment), then broadcast via shfl and consumed from registers.
__device__ __forceinline__ int scan_window(
    const float4* __restrict__ bb, const int* __restrict__ ob,
    int lox, int hix, int loy, int hiy, int loz, int hiz,
    float cx, float cy, float cz, int lane,
    unsigned long long lanemask_lt, int* cand)
{
    const float r2 = r2_thresh();
    const int ny = hiy - loy + 1;
    const int nseg = (hix - lox + 1) * ny;  // <= 9

    // lane-parallel bounds fetch: lane l < nseg loads segment l's (s0, s1)
    int my_s0 = 0, my_s1 = 0;
    if (lane < nseg) {
        const int six = lox + lane / ny;
        const int siy = loy + lane % ny;
        const int rowc = (six * 10 + siy) * 10;
        my_s0 = ob[rowc + loz];
        my_s1 = ob[rowc + hiz + 1];   // z cells contiguous -> one segment
    }

    int K = 0;
    for (int s = 0; s < nseg; ++s) {
        const int s0 = __shfl(my_s0, s, 64);
        const int s1 = __shfl(my_s1, s, 64);
        for (int cur = s0; cur < s1; cur += 64) {
            const int i = cur + lane;
            const bool valid = (i < s1);
            float4 pv;
            if (valid) pv = bb[i];
            else { pv.x = 1e9f; pv.y = 1e9f; pv.z = 1e9f; pv.w = 0.0f; }
            float d2;
            {
#pragma clang fp contract(off)
                float dx = pv.x - cx, dy = pv.y - cy, dz = pv.z - cz;
                d2 = dx * dx + dy * dy + dz * dz;
            }
            const bool in = valid && (d2 < r2);
            const unsigned long long m = __ballot(in);
            if (in) {
                const int pos = K + __popcll(m & lanemask_lt);
                if (pos < CAP) cand[pos] = __float_as_int(pv.w);
            }
            K += __popcll(m);
        }
    }
    return K;
}

// ---------------- Kernel F: fused ball query + grouping ----------------
// 256 threads = 4 waves = 4 consecutive sorted queries. Ball query into LDS;
// group phase in TWO passes of 64 pairs reusing one sf buffer. LDS 20,304 B
// -> 8 blocks/CU = 32 waves/CU (wave cap).
__global__ void __launch_bounds__(256) fused_kernel(
    const float4* __restrict__ binned,   // (B, N)
    const int* __restrict__ off,         // (B, OFF_STRIDE)
    const float* __restrict__ new_xyz,   // (B, NPOINT, 3)
    const float* __restrict__ xyz,       // (B, N, 3)
    const float* __restrict__ ft,        // (B, N, C)
    const int* __restrict__ qperm,       // (B, NPOINT)
    float* __restrict__ out)             // (B, 3+C, NPOINT, NSAMPLE)
{
    __shared__ int cand_s[4][CAP + 4];  // 3136 B (4 sentinel slots per wave)
    __shared__ int sidx[4 * NSAMPLE];   // 512 B
    __shared__ int sj[4];               // 16 B
    __shared__ float sf[64 * 65];       // 16640 B   (total 20304 B)

    const int t = threadIdx.x;
    const int lane = t & 63;
    const int w = t >> 6;   // wave = local query

    const int nwg = B * NPOINT / 4;                 // 2048, % 8 == 0
    const int g = blockIdx.x;
    const int swz = (g & 7) * (nwg / 8) + (g >> 3); // bijective XCD swizzle
    const int b = swz / (NPOINT / 4);
    const int p4 = swz % (NPOINT / 4);

    const int j = qperm[b * NPOINT + p4 * 4 + w];   // original query (broadcast)
    if (lane == 0) sj[w] = j;

    const float cx = new_xyz[((size_t)b * NPOINT + j) * 3 + 0];
    const float cy = new_xyz[((size_t)b * NPOINT + j) * 3 + 1];
    const float cz = new_xyz[((size_t)b * NPOINT + j) * 3 + 2];

    int* cand = cand_s[w];
    int* sout = sidx + w * NSAMPLE;
    const float4* __restrict__ bb = binned + (size_t)b * N;
    const int* __restrict__ ob = off + b * OFF_STRIDE;

    const unsigned long long lanemask_lt = (lane == 63) ? 0x7FFFFFFFFFFFFFFFull
                                                        : ((1ull << lane) - 1ull);

    const int lox = max(0, (int)floorf((cx - 0.1001f) * 10.0f));
    const int hix = min(9, (int)floorf((cx + 0.1001f) * 10.0f));
    const int loy = max(0, (int)floorf((cy - 0.1001f) * 10.0f));
    const int hiy = min(9, (int)floorf((cy + 0.1001f) * 10.0f));
    const int loz = max(0, (int)floorf((cz - 0.1001f) * 10.0f));
    const int hiz = min(9, (int)floorf((cz + 0.1001f) * 10.0f));

    const int K = scan_window(bb, ob, lox, hix, loy, hiy, loz, hiz,
                              cx, cy, cz, lane, lanemask_lt, cand);

    if (K > CAP) {  // pathological density: exact linear rescan (wave-uniform)
        linear_ball_fallback(xyz + (size_t)b * N * 3, cx, cy, cz, lane, lanemask_lt, sout);
    } else {
        rank_select(cand, K, lane, sout);
    }
    __syncthreads();

    const size_t plane = (size_t)NPOINT * NSAMPLE;
    const size_t bbase = (size_t)b * (3 + C) * plane;

    // xyz part: threads 0..127 -> one (query,slot) pair each (direct global)
    if (t < 128) {
        const int id = sidx[t];
        const int jq = sj[t >> 5];
        const int s = t & 31;
        const size_t cb = ((size_t)b * NPOINT + jq) * 3;
        const size_t pb = ((size_t)b * N + id) * 3;
        const size_t obx = bbase + (size_t)jq * NSAMPLE + s;
        {
#pragma clang fp contract(off)
            out[obx + 0 * plane] = xyz[pb + 0] - new_xyz[cb + 0];
            out[obx + 1 * plane] = xyz[pb + 1] - new_xyz[cb + 1];
            out[obx + 2 * plane] = xyz[pb + 2] - new_xyz[cb + 2];
        }
    }

    // group phase: two passes of 64 pairs (queries 2h, 2h+1), sf reused
#pragma unroll
    for (int h = 0; h < 2; ++h) {
        const int* sidxL = sidx + h * 64;
        // gather: 64 pairs x 16 lanes, one float4 each, 4 iterations
        {
            const int lane16 = t & 15;
            const int pg = t >> 4;  // 0..15
#pragma unroll
            for (int it = 0; it < 4; ++it) {
                const int pp = it * 16 + pg;
                const int id = sidxL[pp];
                const float4 v = *(const float4*)(ft + ((size_t)b * N + id) * C + lane16 * 4);
                float* dst = sf + pp * 65 + lane16 * 4;
                dst[0] = v.x; dst[1] = v.y; dst[2] = v.z; dst[3] = v.w;
            }
        }
        __syncthreads();
        // store: float4 per thread = 4 samples of one channel.
        {
            const int f = t & 15;
            const int rl = f >> 3;           // local row 0/1 within this h-pass
            const int s0 = (f & 7) * 4;      // starting sample of the quad
            const int q = sj[2 * h + rl];
            const size_t rowb = bbase + (size_t)q * NSAMPLE + s0;
            const int prow = (rl * 32 + s0) * 65;   // sf row base for this quad
#pragma unroll
            for (int it = 0; it < 4; ++it) {
                const int c = it * 16 + (t >> 4);
                float4 v;
                v.x = sf[prow + 0 * 65 + c];
                v.y = sf[prow + 1 * 65 + c];
                v.z = sf[prow + 2 * 65 + c];
                v.w = sf[prow + 3 * 65 + c];
                *(float4*)(out + rowb + (size_t)(3 + c) * plane) = v;
            }
        }
        __syncthreads();  // before sf reuse in next pass
    }
}

// ---------------- ws-too-small fallbacks (linear ball + direct group) ----------------
__global__ void __launch_bounds__(256) ball_query_kernel(
    const float* __restrict__ xyz, const float* __restrict__ new_xyz,
    int* __restrict__ idx_out)
{
    const int wave = (blockIdx.x * blockDim.x + threadIdx.x) >> 6;
    const int lane = threadIdx.x & 63;
    if (wave >= B * NPOINT) return;
    const int b = wave / NPOINT;
    const float cx = new_xyz[(size_t)wave * 3 + 0];
    const float cy = new_xyz[(size_t)wave * 3 + 1];
    const float cz = new_xyz[(size_t)wave * 3 + 2];
    const unsigned long long lanemask_lt = (lane == 63) ? 0x7FFFFFFFFFFFFFFFull
                                                        : ((1ull << lane) - 1ull);
    linear_ball_fallback(xyz + (size_t)b * N * 3, cx, cy, cz, lane, lanemask_lt,
                         idx_out + (size_t)wave * NSAMPLE);
}

__global__ void __launch_bounds__(256) group_kernel(
    const float* __restrict__ xyz, const float* __restrict__ new_xyz,
    const float* __restrict__ feat, const int* __restrict__ idx_arr,
    float* __restrict__ out) {
    const int t = threadIdx.x;
    const int s = t & 31;
    const int jl = t >> 5;
    const int j = blockIdx.x * 8 + jl;
    const int b = blockIdx.y;

    const int id = idx_arr[((size_t)b * NPOINT + j) * NSAMPLE + s];

    const float px = xyz[((size_t)b * N + id) * 3 + 0] - new_xyz[((size_t)b * NPOINT + j) * 3 + 0];
    const float py = xyz[((size_t)b * N + id) * 3 + 1] - new_xyz[((size_t)b * NPOINT + j) * 3 + 1];
    const float pz = xyz[((size_t)b * N + id) * 3 + 2] - new_xyz[((size_t)b * NPOINT + j) * 3 + 2];

    const size_t plane = (size_t)NPOINT * NSAMPLE;
    const size_t obase = (size_t)b * (3 + C) * plane + (size_t)j * NSAMPLE + s;

    out[obase + 0 * plane] = px;
    out[obase + 1 * plane] = py;
    out[obase + 2 * plane] = pz;

    const float* __restrict__ fb = feat + (size_t)b * C * N;
#pragma unroll 8
    for (int c = 0; c < C; ++c) {
        out[obase + (size_t)(3 + c) * plane] = fb[(size_t)c * N + id];
    }
}

extern "C" void kernel_launch(void* const* d_in, const int* in_sizes, int n_in,
                              void* d_out, int out_size, void* d_ws, size_t ws_size,
                              hipStream_t stream) {
    const float* xyz     = (const float*)d_in[0];  // (B, N, 3)
    const float* new_xyz = (const float*)d_in[1];  // (B, NPOINT, 3)
    const float* feat    = (const float*)d_in[2];  // (B, C, N)
    float* out = (float*)d_out;

    // Workspace layout (contiguous; all segments 16B-aligned)
    const size_t idx_bytes    = (size_t)B * NPOINT * NSAMPLE * sizeof(int);  // fallback only
    const size_t ft_bytes     = (size_t)B * N * C * sizeof(float);           // 8,388,608
    const size_t binned_bytes = (size_t)B * N * sizeof(float4);              //   524,288
    const size_t off_bytes    = (size_t)B * OFF_STRIDE * sizeof(int);        //     8,448
    const size_t cellw_bytes  = (size_t)B * CELLW_STRIDE * sizeof(int);      //     8,192
    const size_t qwork_bytes  = (size_t)B * CELLW_STRIDE * sizeof(int);      //     8,192
    const size_t gcur_bytes   = (size_t)B * CELLW_STRIDE * sizeof(int);      //     8,192
    const size_t qgcur_bytes  = (size_t)B * CELLW_STRIDE * sizeof(int);      //     8,192
    const size_t qperm_bytes  = (size_t)B * NPOINT * sizeof(int);            //    32,768

    char* ws = (char*)d_ws;
    size_t o = 0;
    int*    idx_ws   = (int*)(ws + o);    o += idx_bytes;
    float*  ft       = (float*)(ws + o);  o += ft_bytes;
    float4* binned   = (float4*)(ws + o); o += binned_bytes;
    int*    off      = (int*)(ws + o);    o += off_bytes;
    int*    cellwork = (int*)(ws + o);    o += cellw_bytes;   // cellwork,qwork,gcur,qgcur adjacent
    int*    qwork    = (int*)(ws + o);    o += qwork_bytes;
    int*    gcur     = (int*)(ws + o);    o += gcur_bytes;
    int*    qgcur    = (int*)(ws + o);    o += qgcur_bytes;
    int*    qperm    = (int*)(ws + o);    o += qperm_bytes;

    const bool use_grid = (ws_size >= o);

    if (use_grid) {
        // zero histograms + global cursors (adjacent, one memset)
        hipMemsetAsync(cellwork, 0, cellw_bytes + qwork_bytes + gcur_bytes + qgcur_bytes, stream);
        hist_transpose_kernel<<<HIST_BLOCKS + TRANS_BLOCKS, 256, 0, stream>>>(
            xyz, new_xyz, cellwork, qwork, feat, ft);
        scan_scatter_kernel<<<SS_BLOCKS, 256, 0, stream>>>(
            xyz, new_xyz, cellwork, qwork, off, binned, qperm, gcur, qgcur);
        fused_kernel<<<B * NPOINT / 4, 256, 0, stream>>>(
            binned, off, new_xyz, xyz, ft, qperm, out);
    } else {
        ball_query_kernel<<<(B * NPOINT) / 4, 256, 0, stream>>>(xyz, new_xyz, idx_ws);
        dim3 grid2(NPOINT / 8, B);
        group_kernel<<<grid2, 256, 0, stream>>>(xyz, new_xyz, feat, idx_ws, out);
    }
}